// Round 16
// baseline (29.761 us; speedup 1.0000x reference)
//
#include <hip/hip_runtime.h>
#include <math.h>

#define NQ   12
#define BLK  512
#define IND  768
#define HD   24
#define NOBS 28
#define CSTR 20   // LDS row stride in dwords (80B, 16B-aligned)

typedef float    f32x2 __attribute__((ext_vector_type(2)));
typedef float    f32x4 __attribute__((ext_vector_type(4)));
typedef __fp16   f16x2 __attribute__((ext_vector_type(2)));
typedef _Float16 h8    __attribute__((ext_vector_type(8)));

__device__ __forceinline__ unsigned pkrtz(float x, float y) {
    f16x2 h = __builtin_amdgcn_cvt_pkrtz(x, y);
    unsigned u; __builtin_memcpy(&u, &h, 4); return u;
}
__device__ __forceinline__ f32x2 unpack2(unsigned u) {
    f16x2 h; __builtin_memcpy(&h, &u, 4);
    f32x2 v; v.x = (float)h.x; v.y = (float)h.y; return v;
}
__device__ __forceinline__ f32x2 pk_cmul(f32x2 m, f32x2 u) {
    f32x2 r;
    asm("v_pk_mul_f32 %0, %1, %2 op_sel:[0,0] op_sel_hi:[0,1]"
        : "=v"(r) : "v"(m), "v"(u));
    asm("v_pk_fma_f32 %0, %1, %2, %0 op_sel:[1,1,0] op_sel_hi:[1,0,1] neg_lo:[0,1,0]"
        : "+v"(r) : "v"(m), "v"(u));
    return r;
}
__device__ __forceinline__ void pk_fma_plain(f32x2& acc, f32x2 a, f32x2 b) {
    asm("v_pk_fma_f32 %0, %1, %2, %0" : "+v"(acc) : "v"(a), "v"(b));
}
__device__ __forceinline__ h8 as_h8(uint4 u) { h8 r; __builtin_memcpy(&r, &u, 16); return r; }

__device__ __forceinline__ int pfx12(int y) { y ^= y >> 1; y ^= y >> 2; y ^= y >> 4; y ^= y >> 8; return y; }
__device__ __forceinline__ int pfx8 (int y) { y ^= y >> 1; y ^= y >> 2; y ^= y >> 4; return y; }

// 4-qubit group GEMM stage, 8 waves x 2 N-tiles; double-buffered (src -> dst),
// so only ONE barrier per stage (top). A-fragments preloaded from LDS.
// S = stage index 0..5 ; WM: 0: G0->G1  1: G1->G2  2: G2->G0 +ring  3: G2->meas +ring
template<int S, int WM>
__device__ __forceinline__ void gstage(const unsigned* src, unsigned* dst,
                                       const unsigned* Afr, int l, int w) {
    const int a  = l & 15;
    const int mb = (l >> 4) * 4;

    __syncthreads();                 // prior stage's writes to src visible
    const unsigned* Ap = Afr + (S * 64 + l) * 8;
    const uint4 A04 = *(const uint4*)(Ap);
    const uint4 A14 = *(const uint4*)(Ap + 4);
    uint4 Bf[2];
    #pragma unroll
    for (int tt = 0; tt < 2; ++tt)
        Bf[tt] = *(const uint4*)(src + (16 * (2*w + tt) + a) * CSTR + mb);

    const h8 A0 = as_h8(A04), A1 = as_h8(A14);
    int TL = 0;
    if (WM >= 2) TL = pfx12(mb << 8);
    const int CTJ[4] = {0, 0x1FF, 0x3FF, 0x200};

    #pragma unroll
    for (int tt = 0; tt < 2; ++tt) {
        f32x4 c0 = {0.f, 0.f, 0.f, 0.f}, c1 = {0.f, 0.f, 0.f, 0.f};
        const h8 Bh = as_h8(Bf[tt]);
        c0 = __builtin_amdgcn_mfma_f32_16x16x32_f16(A0, Bh, c0, 0, 0, 0);
        c1 = __builtin_amdgcn_mfma_f32_16x16x32_f16(A1, Bh, c1, 0, 0, 0);
        const int n = 16 * (2*w + tt) + a;
        if (WM == 0) {
            const int base = (mb + (n & 0xF0)) * CSTR + (n & 15);
            #pragma unroll
            for (int j = 0; j < 4; ++j)
                dst[base + j * CSTR] = pkrtz(c0[j], c1[j]);
        } else if (WM == 1) {
            const int base = ((n & 15) + mb * 16) * CSTR + (n >> 4);
            #pragma unroll
            for (int j = 0; j < 4; ++j)
                dst[base + j * 16 * CSTR] = pkrtz(c0[j], c1[j]);
        } else {
            const int TN = pfx8(n) ^ TL;
            #pragma unroll
            for (int j = 0; j < 4; ++j) {
                const int tz = TN ^ CTJ[j];
                const int jp = tz ^ ((tz & 1) << 11);
                const int addr = (WM == 2) ? ((jp >> 4) * CSTR + (jp & 15))
                                           : ((jp & 255) * CSTR + (jp >> 8));
                dst[addr] = pkrtz(c0[j], c1[j]);
            }
        }
    }
}

__global__ void __launch_bounds__(BLK, 4) pqm_kernel(
    const float* __restrict__ x,   const float* __restrict__ W1,
    const float* __restrict__ b1,  const float* __restrict__ ln_g,
    const float* __restrict__ ln_b,const float* __restrict__ W2,
    const float* __restrict__ b2,  const float* __restrict__ qw0,
    const float* __restrict__ qw1, const float* __restrict__ qw2,
    const float* __restrict__ scales, const float* __restrict__ biases,
    float* __restrict__ out)
{
    __shared__ unsigned stA[256 * CSTR];   // 20 KB state buffer A
    __shared__ unsigned stB[256 * CSTR];   // 20 KB state buffer B
    __shared__ unsigned Afr[6 * 64 * 8];   // 12 KB precomputed A-fragments
    __shared__ float GM[3][NQ][8];
    __shared__ float hb[HD];
    __shared__ float ang[2 * NQ];
    __shared__ float wpar[8][22];

    const int t   = threadIdx.x;
    const int w   = t >> 6;          // wave 0..7
    const int l   = t & 63;          // lane
    const int row = blockIdx.x;

    // ---- P1: stage x row ----
    float* xs = (float*)stA;
    if (t < 192) ((float4*)xs)[t] = ((const float4*)(x + row * IND))[t];
    __syncthreads();

    // ---- P2: h = x@W1^T + b1 (24 outs x 16 lanes, 12 float4/lane); Rot mats ----
    {
        int g = t >> 4, l16 = t & 15;
        if (g < HD) {
            const float* wp = W1 + g * IND;
            float acc = 0.f;
            #pragma unroll
            for (int k = 0; k < 12; ++k) {
                const int f4 = l16 + 16 * k;        // float4 index 0..191
                float4 a4 = ((const float4*)xs)[f4];
                float4 w4 = *(const float4*)(wp + 4 * f4);
                acc += a4.x * w4.x + a4.y * w4.y + a4.z * w4.z + a4.w * w4.w;
            }
            acc += __shfl_down(acc, 8, 16);
            acc += __shfl_down(acc, 4, 16);
            acc += __shfl_down(acc, 2, 16);
            acc += __shfl_down(acc, 1, 16);
            if (l16 == 0) hb[g] = acc + b1[g];
        } else if (t >= 448 && t < 484) {
            int u = t - 448; int li = u / NQ, q = u % NQ;
            const float* qw = (li == 0) ? qw0 : ((li == 1) ? qw1 : qw2);
            float phi = qw[q*3+0], th = qw[q*3+1], om = qw[q*3+2];
            float c = cosf(0.5f*th), s = sinf(0.5f*th);
            float sp, cp, sm, cm;
            sincosf(0.5f*(phi+om), &sp, &cp);
            sincosf(0.5f*(phi-om), &sm, &cm);
            float* R = GM[li][q];
            R[0] =  cp*c;  R[1] = -sp*c;
            R[2] = -cm*s;  R[3] = -sm*s;
            R[4] =  cm*s;  R[5] = -sm*s;
            R[6] =  cp*c;  R[7] =  sp*c;
        }
    }
    __syncthreads();

    // ---- P3: LN + ReLU + W2 + tanh -> angles ----
    if (t < NQ) {
        float mu = 0.f;
        #pragma unroll
        for (int j = 0; j < HD; ++j) mu += hb[j];
        mu *= (1.f / HD);
        float var = 0.f;
        #pragma unroll
        for (int j = 0; j < HD; ++j) { float d = hb[j] - mu; var += d * d; }
        var *= (1.f / HD);
        float rinv = 1.f / sqrtf(var + 1e-5f);
        float acc = b2[t];
        #pragma unroll
        for (int j = 0; j < HD; ++j) {
            float hn = (hb[j] - mu) * rinv * ln_g[j] + ln_b[j];
            acc += fmaxf(hn, 0.f) * W2[t * HD + j];
        }
        float a = tanhf(acc);
        ang[t]      = cosf(0.5f * a);
        ang[NQ + t] = sinf(0.5f * a);
    }
    __syncthreads();
    // ---- P4: fuse M = Rot * RY ----
    if (t < 36) {
        int li = t / NQ, q = t % NQ;
        float* R = GM[li][q];
        float r0=R[0],r1=R[1],r2=R[2],r3=R[3],r4=R[4],r5=R[5],r6=R[6],r7=R[7];
        float cr = ang[q], sr = ang[NQ + q];
        R[0] =  r0*cr + r2*sr;  R[1] =  r1*cr + r3*sr;
        R[2] = -r0*sr + r2*cr;  R[3] = -r1*sr + r3*cr;
        R[4] =  r4*cr + r6*sr;  R[5] =  r5*cr + r7*sr;
        R[6] = -r4*sr + r6*cr;  R[7] = -r5*sr + r7*cr;
    }
    __syncthreads();

    // ---- A-fragment precompute: thread (s,lane) builds stage s, lane's frags ----
    if (t < 384) {
        const int s = t >> 6, lane = t & 63;
        const int LI = 1 + s / 3, G = s % 3;
        const int a = lane & 15, mb = (lane >> 4) * 4;
        unsigned* Ap = Afr + (s * 64 + lane) * 8;
        #pragma unroll
        for (int bi = 0; bi < 4; ++bi) {
            const int bq = mb + bi;
            f32x2 u;
            {
                const float* F = GM[LI][11 - 4*G];
                const int off = (a & 1) * 4 + (bq & 1) * 2;
                u.x = F[off]; u.y = F[off + 1];
            }
            #pragma unroll
            for (int p = 1; p < 4; ++p) {
                const float* F = GM[LI][11 - 4*G - p];
                const int off = ((a >> p) & 1) * 4 + ((bq >> p) & 1) * 2;
                f32x2 e; e.x = F[off]; e.y = F[off + 1];
                u = pk_cmul(e, u);
            }
            Ap[bi]     = pkrtz(u.x, -u.y);   // Cr row
            Ap[4 + bi] = pkrtz(u.y,  u.x);   // Ci row
        }
    }

    // ---- Layer 0 on |0..0>: tensor product, 8 amps/thread; ring fold -> G0 (buf A) ----
    // j = (t<<3)|r : t bit u = j bit 3+u (qubit 8-u); r bit k = j bit k (qubit 11-k)
    {
        f32x2 v0[8];
        f32x2 lf; lf.x = 1.f; lf.y = 0.f;
        #pragma unroll
        for (int u = 0; u < 9; ++u) {
            const float* F = GM[0][8 - u];
            const int bit = (t >> u) & 1;
            f32x2 e; e.x = F[bit * 4]; e.y = F[bit * 4 + 1];
            lf = pk_cmul(e, lf);
        }
        {
            const float* F = GM[0][11];
            f32x2 e0; e0.x = F[0]; e0.y = F[1];
            f32x2 e1; e1.x = F[4]; e1.y = F[5];
            v0[0] = pk_cmul(e0, lf); v0[1] = pk_cmul(e1, lf);
        }
        #pragma unroll
        for (int b = 1; b < 3; ++b) {
            const float* F = GM[0][11 - b];
            f32x2 e0; e0.x = F[0]; e0.y = F[1];
            f32x2 e1; e1.x = F[4]; e1.y = F[5];
            #pragma unroll
            for (int r = 0; r < (1 << b); ++r) {
                v0[r | (1 << b)] = pk_cmul(e1, v0[r]);
                v0[r]            = pk_cmul(e0, v0[r]);
            }
        }
        const int TL = pfx12(t << 3);
        #pragma unroll
        for (int r = 0; r < 8; ++r) {
            const int tr = r ^ (r >> 1) ^ (r >> 2);
            const int tz = TL ^ tr;
            const int jp = tz ^ ((tz & 1) << 11);
            stA[(jp >> 4) * CSTR + (jp & 15)] = pkrtz(v0[r].x, v0[r].y);
        }
    }

    // ---- Layers 1 & 2: 6 ping-pong group-GEMM stages (1 barrier each) ----
    gstage<0, 0>(stA, stB, Afr, l, w);
    gstage<1, 1>(stB, stA, Afr, l, w);
    gstage<2, 2>(stA, stB, Afr, l, w);
    gstage<3, 0>(stB, stA, Afr, l, w);
    gstage<4, 1>(stA, stB, Afr, l, w);
    gstage<5, 3>(stB, stA, Afr, l, w);
    __syncthreads();
    const unsigned* stF = stA;       // final state buffer

    // ---- Measurement: amp j at row j&255, dword j>>8 (true final state) ----
    // thread: R = t&255 (j bits 7..0 = qubits 4..11), h = t>>8 (j bit 11 = qubit 0),
    //         reg r = j bits 10..8 (qubits 1,2,3)
    {
        const int R = t & 255, h = t >> 8;
        const int rowb = R * CSTR + 8 * h;
        f32x2 v[8];
        #pragma unroll
        for (int p = 0; p < 4; ++p) {
            uint2 raw = *(const uint2*)(stF + rowb + 2 * p);
            v[2*p]   = unpack2(raw.x);
            v[2*p+1] = unpack2(raw.y);
        }
        float ex[5];
        // q1..q3: register-pair sums (double count over r = required x2)
        #pragma unroll
        for (int q = 1; q <= 3; ++q) {
            f32x2 acc; acc.x = 0.f; acc.y = 0.f;
            const int m = 8 >> q;
            #pragma unroll
            for (int r = 0; r < 8; ++r) pk_fma_plain(acc, v[r], v[r ^ m]);
            ex[q] = acc.x + acc.y;
        }
        // q0: partner = other dword half (j bit 11); thread double-count = x2
        {
            f32x2 acc; acc.x = 0.f; acc.y = 0.f;
            const int pb = R * CSTR + 8 * (h ^ 1);
            #pragma unroll
            for (int p = 0; p < 4; ++p) {
                uint2 raw = *(const uint2*)(stF + pb + 2 * p);
                pk_fma_plain(acc, v[2*p],   unpack2(raw.x));
                pk_fma_plain(acc, v[2*p+1], unpack2(raw.y));
            }
            ex[0] = acc.x + acc.y;
        }
        // q4: partner row R^128 (j bit 7); thread double-count = x2
        {
            f32x2 acc; acc.x = 0.f; acc.y = 0.f;
            const int pb = (R ^ 128) * CSTR + 8 * h;
            #pragma unroll
            for (int p = 0; p < 4; ++p) {
                uint2 raw = *(const uint2*)(stF + pb + 2 * p);
                pk_fma_plain(acc, v[2*p],   unpack2(raw.x));
                pk_fma_plain(acc, v[2*p+1], unpack2(raw.y));
            }
            ex[4] = acc.x + acc.y;
        }

        // probabilities + 3-level register WHT over r (q1,q2,q3)
        #pragma unroll
        for (int r = 0; r < 8; ++r) v[r].x = v[r].x * v[r].x + v[r].y * v[r].y;
        #pragma unroll
        for (int lev = 0; lev < 3; ++lev) {
            const int m = 1 << lev;
            #pragma unroll
            for (int r = 0; r < 8; ++r)
                if (!(r & m)) { float A = v[r].x, B = v[r | m].x; v[r].x = A + B; v[r | m].x = A - B; }
        }

        // lane WHT of W[0] over 6 lane bits (qubits 6..11)
        float ch = v[0].x;
        #pragma unroll
        for (int lev = 0; lev < 6; ++lev) {
            float o = __shfl_xor(ch, 1 << lev, 64);
            ch = (l & (1 << lev)) ? (o - ch) : (ch + o);
        }
        auto wsum = [&](float s) {
            #pragma unroll
            for (int d = 1; d < 64; d <<= 1) s += __shfl_xor(s, d, 64);
            return s;
        };
        float W4 = wsum(v[4].x), W2 = wsum(v[2].x), W1s = wsum(v[1].x);
        float W6 = wsum(v[6].x), W3 = wsum(v[3].x);
        float e0 = wsum(ex[0]), e1 = wsum(ex[1]), e2 = wsum(ex[2]);
        float e3 = wsum(ex[3]), e4 = wsum(ex[4]);

        if      (l == 0) {
            wpar[w][0]  = ch;
            wpar[w][12] = W4;  wpar[w][13] = W2; wpar[w][14] = W1s;
            wpar[w][15] = W6;  wpar[w][16] = W3;
            wpar[w][17] = e0;  wpar[w][18] = e1; wpar[w][19] = e2;
            wpar[w][20] = e3;  wpar[w][21] = e4;
        }
        else if (l == 32) wpar[w][1]  = ch;
        else if (l == 16) wpar[w][2]  = ch;
        else if (l == 8)  wpar[w][3]  = ch;
        else if (l == 4)  wpar[w][4]  = ch;
        else if (l == 2)  wpar[w][5]  = ch;
        else if (l == 1)  wpar[w][6]  = ch;
        else if (l == 48) wpar[w][7]  = ch;
        else if (l == 24) wpar[w][8]  = ch;
        else if (l == 12) wpar[w][9]  = ch;
        else if (l == 6)  wpar[w][10] = ch;
        else if (l == 3)  wpar[w][11] = ch;
    }
    __syncthreads();

    if (t < NOBS) {
        // observable -> (per-wave slot, wave-sign mask: w bit0=q5, bit1=q4, bit2=q0)
        const int oslot[NOBS] = {0,12,13,14, 0,0, 1,2,3,4,5,6,
                                 12,15,16,14, 0,1, 7,8,9,10,11,
                                 17,18,19,20,21};
        const int omw[NOBS]   = {4,0,0,0, 2,1, 0,0,0,0,0,0,
                                 4,0,0,2, 3,1, 0,0,0,0,0,
                                 0,0,0,0,0};
        const int sl = oslot[t], mw = omw[t];
        float s = 0.f;
        #pragma unroll
        for (int g = 0; g < 8; ++g) {
            float p = wpar[g][sl];
            s += (__popc(g & mw) & 1) ? -p : p;
        }
        out[row * NOBS + t] = s * scales[t] + biases[t];
    }
}

extern "C" void kernel_launch(void* const* d_in, const int* in_sizes, int n_in,
                              void* d_out, int out_size, void* d_ws, size_t ws_size,
                              hipStream_t stream) {
    const int Bn = in_sizes[0] / IND;   // 1024
    pqm_kernel<<<dim3(Bn), dim3(BLK), 0, stream>>>(
        (const float*)d_in[0], (const float*)d_in[1], (const float*)d_in[2],
        (const float*)d_in[3], (const float*)d_in[4], (const float*)d_in[5],
        (const float*)d_in[6], (const float*)d_in[7], (const float*)d_in[8],
        (const float*)d_in[9], (const float*)d_in[10], (const float*)d_in[11],
        (float*)d_out);
}

// Round 17
// 26.627 us; speedup vs baseline: 1.1177x; 1.1177x over previous
//
#include <hip/hip_runtime.h>
#include <math.h>

#define NQ   12
#define BLK  512
#define IND  768
#define HD   24
#define NOBS 28
#define CSTR 20   // LDS row stride in dwords (80B, 16B-aligned)

typedef float    f32x2 __attribute__((ext_vector_type(2)));
typedef float    f32x4 __attribute__((ext_vector_type(4)));
typedef __fp16   f16x2 __attribute__((ext_vector_type(2)));
typedef _Float16 h8    __attribute__((ext_vector_type(8)));

__device__ __forceinline__ unsigned pkrtz(float x, float y) {
    f16x2 h = __builtin_amdgcn_cvt_pkrtz(x, y);
    unsigned u; __builtin_memcpy(&u, &h, 4); return u;
}
__device__ __forceinline__ f32x2 unpack2(unsigned u) {
    f16x2 h; __builtin_memcpy(&h, &u, 4);
    f32x2 v; v.x = (float)h.x; v.y = (float)h.y; return v;
}
__device__ __forceinline__ f32x2 pk_cmul(f32x2 m, f32x2 u) {
    f32x2 r;
    asm("v_pk_mul_f32 %0, %1, %2 op_sel:[0,0] op_sel_hi:[0,1]"
        : "=v"(r) : "v"(m), "v"(u));
    asm("v_pk_fma_f32 %0, %1, %2, %0 op_sel:[1,1,0] op_sel_hi:[1,0,1] neg_lo:[0,1,0]"
        : "+v"(r) : "v"(m), "v"(u));
    return r;
}
__device__ __forceinline__ void pk_fma_plain(f32x2& acc, f32x2 a, f32x2 b) {
    asm("v_pk_fma_f32 %0, %1, %2, %0" : "+v"(acc) : "v"(a), "v"(b));
}
__device__ __forceinline__ h8 as_h8(uint4 u) { h8 r; __builtin_memcpy(&r, &u, 16); return r; }

__device__ __forceinline__ int pfx12(int y) { y ^= y >> 1; y ^= y >> 2; y ^= y >> 4; y ^= y >> 8; return y; }
__device__ __forceinline__ int pfx8 (int y) { y ^= y >> 1; y ^= y >> 2; y ^= y >> 4; return y; }

// 4-qubit group GEMM stage, 8 waves x 2 N-tiles; A-fragments preloaded from LDS.
// S = stage index 0..5 ; WM: 0: G0->G1  1: G1->G2  2: G2->G0 +ring  3: G2->meas +ring
template<int S, int WM>
__device__ __forceinline__ void gstage(unsigned* st, const unsigned* Afr,
                                       int l, int w) {
    const int a  = l & 15;
    const int mb = (l >> 4) * 4;

    __syncthreads();                 // prior stage writes visible
    const unsigned* Ap = Afr + (S * 64 + l) * 8;
    const uint4 A04 = *(const uint4*)(Ap);
    const uint4 A14 = *(const uint4*)(Ap + 4);
    uint4 Bf[2];
    #pragma unroll
    for (int tt = 0; tt < 2; ++tt)
        Bf[tt] = *(const uint4*)(st + (16 * (2*w + tt) + a) * CSTR + mb);
    __syncthreads();                 // all reads done before any write

    const h8 A0 = as_h8(A04), A1 = as_h8(A14);
    int TL = 0;
    if (WM >= 2) TL = pfx12(mb << 8);
    const int CTJ[4] = {0, 0x1FF, 0x3FF, 0x200};

    #pragma unroll
    for (int tt = 0; tt < 2; ++tt) {
        f32x4 c0 = {0.f, 0.f, 0.f, 0.f}, c1 = {0.f, 0.f, 0.f, 0.f};
        const h8 Bh = as_h8(Bf[tt]);
        c0 = __builtin_amdgcn_mfma_f32_16x16x32_f16(A0, Bh, c0, 0, 0, 0);
        c1 = __builtin_amdgcn_mfma_f32_16x16x32_f16(A1, Bh, c1, 0, 0, 0);
        const int n = 16 * (2*w + tt) + a;
        if (WM == 0) {
            const int base = (mb + (n & 0xF0)) * CSTR + (n & 15);
            #pragma unroll
            for (int j = 0; j < 4; ++j)
                st[base + j * CSTR] = pkrtz(c0[j], c1[j]);
        } else if (WM == 1) {
            const int base = ((n & 15) + mb * 16) * CSTR + (n >> 4);
            #pragma unroll
            for (int j = 0; j < 4; ++j)
                st[base + j * 16 * CSTR] = pkrtz(c0[j], c1[j]);
        } else {
            const int TN = pfx8(n) ^ TL;
            #pragma unroll
            for (int j = 0; j < 4; ++j) {
                const int tz = TN ^ CTJ[j];
                const int jp = tz ^ ((tz & 1) << 11);
                const int addr = (WM == 2) ? ((jp >> 4) * CSTR + (jp & 15))
                                           : ((jp & 255) * CSTR + (jp >> 8));
                st[addr] = pkrtz(c0[j], c1[j]);
            }
        }
    }
}

__global__ void __launch_bounds__(BLK, 4) pqm_kernel(
    const float* __restrict__ x,   const float* __restrict__ W1,
    const float* __restrict__ b1,  const float* __restrict__ ln_g,
    const float* __restrict__ ln_b,const float* __restrict__ W2,
    const float* __restrict__ b2,  const float* __restrict__ qw0,
    const float* __restrict__ qw1, const float* __restrict__ qw2,
    const float* __restrict__ scales, const float* __restrict__ biases,
    float* __restrict__ out)
{
    __shared__ unsigned st[256 * CSTR];    // 20 KB state
    __shared__ unsigned Afr[6 * 64 * 8];   // 12 KB precomputed A-fragments
    __shared__ float GM[3][NQ][8];
    __shared__ float hb[HD];
    __shared__ float ang[2 * NQ];
    __shared__ float wpar[8][22];

    const int t   = threadIdx.x;
    const int w   = t >> 6;          // wave 0..7
    const int l   = t & 63;          // lane
    const int row = blockIdx.x;

    // ---- P1: stage x row ----
    float* xs = (float*)st;
    if (t < 192) ((float4*)xs)[t] = ((const float4*)(x + row * IND))[t];
    __syncthreads();

    // ---- P2: h = x@W1^T + b1 (24 outs x 16 lanes, 12 float4/lane); Rot mats ----
    {
        int g = t >> 4, l16 = t & 15;
        if (g < HD) {
            const float* wp = W1 + g * IND;
            float acc = 0.f;
            #pragma unroll
            for (int k = 0; k < 12; ++k) {
                const int f4 = l16 + 16 * k;        // float4 index 0..191
                float4 a4 = ((const float4*)xs)[f4];
                float4 w4 = *(const float4*)(wp + 4 * f4);
                acc += a4.x * w4.x + a4.y * w4.y + a4.z * w4.z + a4.w * w4.w;
            }
            acc += __shfl_down(acc, 8, 16);
            acc += __shfl_down(acc, 4, 16);
            acc += __shfl_down(acc, 2, 16);
            acc += __shfl_down(acc, 1, 16);
            if (l16 == 0) hb[g] = acc + b1[g];
        } else if (t >= 448 && t < 484) {
            int u = t - 448; int li = u / NQ, q = u % NQ;
            const float* qw = (li == 0) ? qw0 : ((li == 1) ? qw1 : qw2);
            float phi = qw[q*3+0], th = qw[q*3+1], om = qw[q*3+2];
            float c = cosf(0.5f*th), s = sinf(0.5f*th);
            float sp, cp, sm, cm;
            sincosf(0.5f*(phi+om), &sp, &cp);
            sincosf(0.5f*(phi-om), &sm, &cm);
            float* R = GM[li][q];
            R[0] =  cp*c;  R[1] = -sp*c;
            R[2] = -cm*s;  R[3] = -sm*s;
            R[4] =  cm*s;  R[5] = -sm*s;
            R[6] =  cp*c;  R[7] =  sp*c;
        }
    }
    __syncthreads();

    // ---- P3: LN + ReLU + W2 + tanh -> angles ----
    if (t < NQ) {
        float mu = 0.f;
        #pragma unroll
        for (int j = 0; j < HD; ++j) mu += hb[j];
        mu *= (1.f / HD);
        float var = 0.f;
        #pragma unroll
        for (int j = 0; j < HD; ++j) { float d = hb[j] - mu; var += d * d; }
        var *= (1.f / HD);
        float rinv = 1.f / sqrtf(var + 1e-5f);
        float acc = b2[t];
        #pragma unroll
        for (int j = 0; j < HD; ++j) {
            float hn = (hb[j] - mu) * rinv * ln_g[j] + ln_b[j];
            acc += fmaxf(hn, 0.f) * W2[t * HD + j];
        }
        float a = tanhf(acc);
        ang[t]      = cosf(0.5f * a);
        ang[NQ + t] = sinf(0.5f * a);
    }
    __syncthreads();
    // ---- P4: fuse M = Rot * RY ----
    if (t < 36) {
        int li = t / NQ, q = t % NQ;
        float* R = GM[li][q];
        float r0=R[0],r1=R[1],r2=R[2],r3=R[3],r4=R[4],r5=R[5],r6=R[6],r7=R[7];
        float cr = ang[q], sr = ang[NQ + q];
        R[0] =  r0*cr + r2*sr;  R[1] =  r1*cr + r3*sr;
        R[2] = -r0*sr + r2*cr;  R[3] = -r1*sr + r3*cr;
        R[4] =  r4*cr + r6*sr;  R[5] =  r5*cr + r7*sr;
        R[6] = -r4*sr + r6*cr;  R[7] = -r5*sr + r7*cr;
    }
    __syncthreads();

    // ---- A-fragment precompute: thread (s,lane) builds stage s, lane's frags ----
    if (t < 384) {
        const int s = t >> 6, lane = t & 63;
        const int LI = 1 + s / 3, G = s % 3;
        const int a = lane & 15, mb = (lane >> 4) * 4;
        unsigned* Ap = Afr + (s * 64 + lane) * 8;
        #pragma unroll
        for (int bi = 0; bi < 4; ++bi) {
            const int bq = mb + bi;
            f32x2 u;
            {
                const float* F = GM[LI][11 - 4*G];
                const int off = (a & 1) * 4 + (bq & 1) * 2;
                u.x = F[off]; u.y = F[off + 1];
            }
            #pragma unroll
            for (int p = 1; p < 4; ++p) {
                const float* F = GM[LI][11 - 4*G - p];
                const int off = ((a >> p) & 1) * 4 + ((bq >> p) & 1) * 2;
                f32x2 e; e.x = F[off]; e.y = F[off + 1];
                u = pk_cmul(e, u);
            }
            Ap[bi]     = pkrtz(u.x, -u.y);   // Cr row
            Ap[4 + bi] = pkrtz(u.y,  u.x);   // Ci row
        }
    }

    // ---- Layer 0 on |0..0>: tensor product, 8 amps/thread; ring fold -> G0 ----
    // j = (t<<3)|r : t bit u = j bit 3+u (qubit 8-u); r bit k = j bit k (qubit 11-k)
    {
        f32x2 v0[8];
        f32x2 lf; lf.x = 1.f; lf.y = 0.f;
        #pragma unroll
        for (int u = 0; u < 9; ++u) {
            const float* F = GM[0][8 - u];
            const int bit = (t >> u) & 1;
            f32x2 e; e.x = F[bit * 4]; e.y = F[bit * 4 + 1];
            lf = pk_cmul(e, lf);
        }
        {
            const float* F = GM[0][11];
            f32x2 e0; e0.x = F[0]; e0.y = F[1];
            f32x2 e1; e1.x = F[4]; e1.y = F[5];
            v0[0] = pk_cmul(e0, lf); v0[1] = pk_cmul(e1, lf);
        }
        #pragma unroll
        for (int b = 1; b < 3; ++b) {
            const float* F = GM[0][11 - b];
            f32x2 e0; e0.x = F[0]; e0.y = F[1];
            f32x2 e1; e1.x = F[4]; e1.y = F[5];
            #pragma unroll
            for (int r = 0; r < (1 << b); ++r) {
                v0[r | (1 << b)] = pk_cmul(e1, v0[r]);
                v0[r]            = pk_cmul(e0, v0[r]);
            }
        }
        const int TL = pfx12(t << 3);
        #pragma unroll
        for (int r = 0; r < 8; ++r) {
            const int tr = r ^ (r >> 1) ^ (r >> 2);
            const int tz = TL ^ tr;
            const int jp = tz ^ ((tz & 1) << 11);
            st[(jp >> 4) * CSTR + (jp & 15)] = pkrtz(v0[r].x, v0[r].y);
        }
    }

    // ---- Layers 1 & 2: 6 group-GEMM stages (A from LDS) ----
    gstage<0, 0>(st, Afr, l, w);
    gstage<1, 1>(st, Afr, l, w);
    gstage<2, 2>(st, Afr, l, w);
    gstage<3, 0>(st, Afr, l, w);
    gstage<4, 1>(st, Afr, l, w);
    gstage<5, 3>(st, Afr, l, w);
    __syncthreads();

    // ---- Measurement: amp j at row j&255, dword j>>8 (true final state) ----
    // thread: R = t&255 (j bits 7..0 = qubits 4..11), h = t>>8 (j bit 11 = qubit 0),
    //         reg r = j bits 10..8 (qubits 1,2,3)
    {
        const int R = t & 255, h = t >> 8;
        const int rowb = R * CSTR + 8 * h;
        f32x2 v[8];
        #pragma unroll
        for (int p = 0; p < 4; ++p) {
            uint2 raw = *(const uint2*)(st + rowb + 2 * p);
            v[2*p]   = unpack2(raw.x);
            v[2*p+1] = unpack2(raw.y);
        }
        float ex[5];
        // q1..q3: register-pair sums (double count over r = required x2)
        #pragma unroll
        for (int q = 1; q <= 3; ++q) {
            f32x2 acc; acc.x = 0.f; acc.y = 0.f;
            const int m = 8 >> q;
            #pragma unroll
            for (int r = 0; r < 8; ++r) pk_fma_plain(acc, v[r], v[r ^ m]);
            ex[q] = acc.x + acc.y;
        }
        // q0: partner = other dword half (j bit 11); thread double-count = x2
        {
            f32x2 acc; acc.x = 0.f; acc.y = 0.f;
            const int pb = R * CSTR + 8 * (h ^ 1);
            #pragma unroll
            for (int p = 0; p < 4; ++p) {
                uint2 raw = *(const uint2*)(st + pb + 2 * p);
                pk_fma_plain(acc, v[2*p],   unpack2(raw.x));
                pk_fma_plain(acc, v[2*p+1], unpack2(raw.y));
            }
            ex[0] = acc.x + acc.y;
        }
        // q4: partner row R^128 (j bit 7); thread double-count = x2
        {
            f32x2 acc; acc.x = 0.f; acc.y = 0.f;
            const int pb = (R ^ 128) * CSTR + 8 * h;
            #pragma unroll
            for (int p = 0; p < 4; ++p) {
                uint2 raw = *(const uint2*)(st + pb + 2 * p);
                pk_fma_plain(acc, v[2*p],   unpack2(raw.x));
                pk_fma_plain(acc, v[2*p+1], unpack2(raw.y));
            }
            ex[4] = acc.x + acc.y;
        }

        // probabilities + 3-level register WHT over r (q1,q2,q3)
        #pragma unroll
        for (int r = 0; r < 8; ++r) v[r].x = v[r].x * v[r].x + v[r].y * v[r].y;
        #pragma unroll
        for (int lev = 0; lev < 3; ++lev) {
            const int m = 1 << lev;
            #pragma unroll
            for (int r = 0; r < 8; ++r)
                if (!(r & m)) { float A = v[r].x, B = v[r | m].x; v[r].x = A + B; v[r | m].x = A - B; }
        }

        // lane WHT of W[0] over 6 lane bits (qubits 6..11)
        float ch = v[0].x;
        #pragma unroll
        for (int lev = 0; lev < 6; ++lev) {
            float o = __shfl_xor(ch, 1 << lev, 64);
            ch = (l & (1 << lev)) ? (o - ch) : (ch + o);
        }
        auto wsum = [&](float s) {
            #pragma unroll
            for (int d = 1; d < 64; d <<= 1) s += __shfl_xor(s, d, 64);
            return s;
        };
        float W4 = wsum(v[4].x), W2 = wsum(v[2].x), W1s = wsum(v[1].x);
        float W6 = wsum(v[6].x), W3 = wsum(v[3].x);
        float e0 = wsum(ex[0]), e1 = wsum(ex[1]), e2 = wsum(ex[2]);
        float e3 = wsum(ex[3]), e4 = wsum(ex[4]);

        if      (l == 0) {
            wpar[w][0]  = ch;
            wpar[w][12] = W4;  wpar[w][13] = W2; wpar[w][14] = W1s;
            wpar[w][15] = W6;  wpar[w][16] = W3;
            wpar[w][17] = e0;  wpar[w][18] = e1; wpar[w][19] = e2;
            wpar[w][20] = e3;  wpar[w][21] = e4;
        }
        else if (l == 32) wpar[w][1]  = ch;
        else if (l == 16) wpar[w][2]  = ch;
        else if (l == 8)  wpar[w][3]  = ch;
        else if (l == 4)  wpar[w][4]  = ch;
        else if (l == 2)  wpar[w][5]  = ch;
        else if (l == 1)  wpar[w][6]  = ch;
        else if (l == 48) wpar[w][7]  = ch;
        else if (l == 24) wpar[w][8]  = ch;
        else if (l == 12) wpar[w][9]  = ch;
        else if (l == 6)  wpar[w][10] = ch;
        else if (l == 3)  wpar[w][11] = ch;
    }
    __syncthreads();

    if (t < NOBS) {
        // observable -> (per-wave slot, wave-sign mask: w bit0=q5, bit1=q4, bit2=q0)
        const int oslot[NOBS] = {0,12,13,14, 0,0, 1,2,3,4,5,6,
                                 12,15,16,14, 0,1, 7,8,9,10,11,
                                 17,18,19,20,21};
        const int omw[NOBS]   = {4,0,0,0, 2,1, 0,0,0,0,0,0,
                                 4,0,0,2, 3,1, 0,0,0,0,0,
                                 0,0,0,0,0};
        const int sl = oslot[t], mw = omw[t];
        float s = 0.f;
        #pragma unroll
        for (int g = 0; g < 8; ++g) {
            float p = wpar[g][sl];
            s += (__popc(g & mw) & 1) ? -p : p;
        }
        out[row * NOBS + t] = s * scales[t] + biases[t];
    }
}

extern "C" void kernel_launch(void* const* d_in, const int* in_sizes, int n_in,
                              void* d_out, int out_size, void* d_ws, size_t ws_size,
                              hipStream_t stream) {
    const int Bn = in_sizes[0] / IND;   // 1024
    pqm_kernel<<<dim3(Bn), dim3(BLK), 0, stream>>>(
        (const float*)d_in[0], (const float*)d_in[1], (const float*)d_in[2],
        (const float*)d_in[3], (const float*)d_in[4], (const float*)d_in[5],
        (const float*)d_in[6], (const float*)d_in[7], (const float*)d_in[8],
        (const float*)d_in[9], (const float*)d_in[10], (const float*)d_in[11],
        (float*)d_out);
}